// Round 18
// baseline (166.931 us; speedup 1.0000x reference)
//
#include <hip/hip_runtime.h>

#define K_C    500
#define KPAD   512
#define DIM    768
#define NROWS  65536
#define BM     64
#define BK     64
#define NKT    (DIM / BK)      // 12 K-tiles
#define THREADS 512
#define TAU    1.0f

// ---- d_ws layout (bytes) ----
#define WS_CSQ  64
#define WS_LIST 4096
#define WS_CHI  270336
#define WS_CT   (270336 + 786432)          // 1056768: fp32 transposed centers
#define WS_NEED (WS_CT + 192 * 512 * 16)   // 2629632 bytes total

typedef __attribute__((ext_vector_type(8)))  short bf16x8;
typedef __attribute__((ext_vector_type(16))) float f32x16;

__device__ __forceinline__ ushort f2bf(float f) {
    unsigned x = __float_as_uint(f);
    unsigned r = (x + 0x7fffu + ((x >> 16) & 1u)) >> 16;   // RNE
    return (ushort)r;
}

#define GLOAD16(g, l)                                                        \
    __builtin_amdgcn_global_load_lds(                                        \
        (__attribute__((address_space(1))) void*)(g),                        \
        (__attribute__((address_space(3))) void*)(l), 16, 0, 0)

// ---------------------------------------------------------------------------
// Pre-kernel 1: centers fp32 -> bf16 (RNE), GLOBAL chunk-major layout:
// unit u = g*512 + r (chunk g 0..95, center r 0..511) holds c[r][g*8..+7].
// ALSO writes fp32 transposed quads ct4[dq*512 + r] = c[r][dq*4..+3]
// for the coalesced rescue path (if do_ct). Zero-pads rows 500..511.
// ---------------------------------------------------------------------------
__global__ void convert_kernel(const float* __restrict__ c, ushort* __restrict__ chi,
                               float4* __restrict__ ct4, int do_ct,
                               int* __restrict__ count) {
    int gid = blockIdx.x * 256 + threadIdx.x;
    if (gid == 0) *count = 0;
    int g = gid >> 9;
    int r = gid & 511;
    int kbase = g * 8;

    float v[8];
    if (r < K_C) {
        #pragma unroll
        for (int e = 0; e < 8; ++e) v[e] = c[(size_t)r * DIM + kbase + e];
    } else {
        #pragma unroll
        for (int e = 0; e < 8; ++e) v[e] = 0.f;
    }
    ushort* ph = chi + (size_t)gid * 8;
    #pragma unroll
    for (int e = 0; e < 8; ++e) ph[e] = f2bf(v[e]);

    if (do_ct) {
        ct4[(size_t)(g * 2 + 0) * 512 + r] = make_float4(v[0], v[1], v[2], v[3]);
        ct4[(size_t)(g * 2 + 1) * 512 + r] = make_float4(v[4], v[5], v[6], v[7]);
    }
}

// ---------------------------------------------------------------------------
// Pre-kernel 2: csq[k] = ||c_k||^2 fp32; pads 500..511 with +INF.
// ---------------------------------------------------------------------------
__global__ void csq_kernel(const float* __restrict__ c, float* __restrict__ csq) {
    int wid  = (blockIdx.x * blockDim.x + threadIdx.x) >> 6;
    int lane = threadIdx.x & 63;
    if (wid >= KPAD) return;
    if (wid >= K_C) { if (lane == 0) csq[wid] = INFINITY; return; }
    const float* row = c + (size_t)wid * DIM;
    float s = 0.f;
    #pragma unroll
    for (int j = 0; j < DIM / 64; ++j) {
        float v = row[lane + j * 64];
        s += v * v;
    }
    #pragma unroll
    for (int m = 32; m; m >>= 1) s += __shfl_xor(s, m, 64);
    if (lane == 0) csq[wid] = s;
}

// ---------------------------------------------------------------------------
// Main kernel (round 18): r16 + STAGGERED K-PHASE.
// All blocks reading the SAME ws B-tile region in lockstep is the suspected
// staging-rate limiter (explains r8-r16 wall AND r12/r15's direct-to-reg
// wall). Block starts its K-loop at phase = (blockIdx>>3) % 12 and wraps:
// at any instant an XCD's resident blocks spread across all 12 B-tiles
// (768 KB) instead of one 64 KB hot-spot. fp32 accumulation order changes
// per block; rounding deltas (~1e-5) << TAU=1.0 are absorbed by the rescue.
// Everything else identical to r16 (BM=64, BK=64, 2 blocks/CU, acc 64).
// ---------------------------------------------------------------------------
__global__ __launch_bounds__(THREADS, 4) void kmeans_mfma(
        const float* __restrict__ x, const char* __restrict__ ws,
        int* __restrict__ out) {
    __shared__ __align__(16) ushort Bh[8][KPAD][8];      // 64 KB
    __shared__ __align__(16) ushort Ah[8][BM][8];        // 8 KB
    __shared__ float rv1[4][BM];                         // 1 KB
    __shared__ float rv2[4][BM];                         // 1 KB
    __shared__ int   ridx[4][BM];                        // 1 KB

    const int tid  = threadIdx.x;
    const int w    = tid >> 6;          // wave 0..7
    const int lane = tid & 63;
    const int l31  = lane & 31;
    const int lh   = lane >> 5;
    const int wm   = w >> 2;            // 0..1 row half (32 rows each)
    const int wn   = w & 3;             // 0..3 col quarter (128 cols each)
    const int rowBase = blockIdx.x * BM;
    const int phase = (blockIdx.x >> 3) % NKT;   // stagger start tile

    // A staging (ALL 512 threads): thread t -> row t>>3 (0..63), chunk j = t&7
    const int srow = tid >> 3;
    const int sj   = tid & 7;
    const int sslot = srow ^ (sj << 1);   // bank-spread write slot
    const float* xsrc = x + (size_t)(rowBase + srow) * DIM + sj * 8;

    const char* wsChi = ws + WS_CHI;
    const float* csq  = (const float*)(ws + WS_CSQ);
    int* count = (int*)ws;
    int* list  = (int*)(ws + WS_LIST);

    f32x16 acc[4] = {};

    // ---- preload + convert A tile `phase` ----
    uint4 hv;
    {
        float4 xa = *reinterpret_cast<const float4*>(xsrc + phase * BK);
        float4 xb = *reinterpret_cast<const float4*>(xsrc + phase * BK + 4);
        float v[8] = {xa.x, xa.y, xa.z, xa.w, xb.x, xb.y, xb.z, xb.w};
        uint h[8];
        #pragma unroll
        for (int e = 0; e < 8; ++e) h[e] = f2bf(v[e]);
        hv = make_uint4(h[0] | (h[1] << 16), h[2] | (h[3] << 16),
                        h[4] | (h[5] << 16), h[6] | (h[7] << 16));
    }

    for (int i = 0; i < NKT; ++i) {
        const int kt  = (i + phase < NKT) ? i + phase : i + phase - NKT;
        const int kt2 = (kt + 1 < NKT) ? kt + 1 : 0;   // next tile in sequence

        __syncthreads();   // (a) prev compute done; Bh/Ah safe to overwrite

        // ---- stage B(kt): 8 waves x 8 KB = 64 KB via global_load_lds ----
        {
            const char* sH = wsChi + (size_t)kt * 65536 + w * 8192 + lane * 16;
            char* dH = ((char*)Bh) + w * 8192;
            #pragma unroll
            for (int q = 0; q < 8; ++q) GLOAD16(sH + q * 1024, dH + q * 1024);
        }
        // ---- A write (pre-converted regs -> LDS, swizzled slot) ----
        *reinterpret_cast<uint4*>(&Ah[sj][sslot][0]) = hv;

        __syncthreads();   // (b) compiler drains vmcnt+lgkm: staged data visible

        // ---- prefetch next A floats (hidden under compute) ----
        float4 xa, xb;
        if (i + 1 < NKT) {
            xa = *reinterpret_cast<const float4*>(xsrc + kt2 * BK);
            xb = *reinterpret_cast<const float4*>(xsrc + kt2 * BK + 4);
        }

        // ---- compute: 4 k-steps of 16, 4 MFMAs each ----
        __builtin_amdgcn_s_setprio(1);
        #pragma unroll
        for (int ks = 0; ks < 4; ++ks) {
            const int j = ks * 2 + lh;                     // chunk 0..7
            const int rsl = (wm * 32 + l31) ^ (j << 1);    // read slot (swizzle inverse)
            bf16x8 ah0 = *(const bf16x8*)&Ah[j][rsl][0];

            const ushort* pBh = &Bh[j][wn * 128 + l31][0];
            #pragma unroll
            for (int nf = 0; nf < 4; ++nf) {
                bf16x8 bh = *(const bf16x8*)(pBh + nf * 32 * 8);
                acc[nf] = __builtin_amdgcn_mfma_f32_32x32x16_bf16(ah0, bh, acc[nf], 0, 0, 0);
            }
        }
        __builtin_amdgcn_s_setprio(0);

        // ---- convert next A tile ----
        if (i + 1 < NKT) {
            float v[8] = {xa.x, xa.y, xa.z, xa.w, xb.x, xb.y, xb.z, xb.w};
            uint h[8];
            #pragma unroll
            for (int e = 0; e < 8; ++e) h[e] = f2bf(v[e]);
            hv = make_uint4(h[0] | (h[1] << 16), h[2] | (h[3] << 16),
                            h[4] | (h[5] << 16), h[6] | (h[7] << 16));
        }
    }

    // ---- epilogue: per-row (best, second, idx) over this wave's 128 cols ----
    float cq[4];
    #pragma unroll
    for (int nf = 0; nf < 4; ++nf) cq[nf] = csq[wn * 128 + nf * 32 + l31];

    #pragma unroll
    for (int reg = 0; reg < 16; ++reg) {
        float v[4]; int col[4];
        #pragma unroll
        for (int nf = 0; nf < 4; ++nf) {
            v[nf]   = fmaf(-2.f, acc[nf][reg], cq[nf]);
            col[nf] = wn * 128 + nf * 32 + l31;
        }
        float paL, paH; int paI;
        if (v[1] < v[0]) { paL = v[1]; paI = col[1]; paH = v[0]; }
        else             { paL = v[0]; paI = col[0]; paH = v[1]; }
        float pbL, pbH; int pbI;
        if (v[3] < v[2]) { pbL = v[3]; pbI = col[3]; pbH = v[2]; }
        else             { pbL = v[2]; pbI = col[2]; pbH = v[3]; }
        float b1, b2; int i1;
        if (pbL < paL) { b1 = pbL; i1 = pbI; b2 = fminf(paL, pbH); }
        else           { b1 = paL; i1 = paI; b2 = fminf(pbL, paH); }
        #pragma unroll
        for (int m = 1; m < 32; m <<= 1) {
            float o1 = __shfl_xor(b1, m, 64);
            float o2 = __shfl_xor(b2, m, 64);
            int   oi = __shfl_xor(i1, m, 64);
            b2 = fminf(fminf(b2, o2), fmaxf(b1, o1));
            if (o1 < b1 || (o1 == b1 && oi < i1)) { b1 = o1; i1 = oi; }
        }
        int row = wm * 32 + (reg & 3) + 8 * (reg >> 2) + 4 * lh;
        if (l31 == 0) { rv1[wn][row] = b1; rv2[wn][row] = b2; ridx[wn][row] = i1; }
    }
    __syncthreads();

    // ---- merge 4 col-quarters per row, write out, flag tight margins ----
    if (tid < BM) {
        float b1 = INFINITY, b2 = INFINITY; int i1 = 0;
        #pragma unroll
        for (int ww = 0; ww < 4; ++ww) {
            float a1 = rv1[ww][tid], a2 = rv2[ww][tid];
            int   ai = ridx[ww][tid];
            b2 = fminf(fminf(b2, a2), fmaxf(b1, a1));
            if (a1 < b1 || (a1 == b1 && ai < i1)) { b1 = a1; i1 = ai; }
        }
        out[rowBase + tid] = i1;
        if (b2 - b1 < TAU) {
            int p = atomicAdd(count, 1);
            list[p] = rowBase + tid;
        }
    }
}

// ---------------------------------------------------------------------------
// Rescue v5 (unchanged): exact fp32, register-tiled, coalesced ct4 loads
// (row-major fallback when ws is too small for the transposed copy).
// ---------------------------------------------------------------------------
#define FMA_BLOCK                                                             \
    {                                                                         \
        _Pragma("unroll")                                                     \
        for (int i = 0; i < 8; ++i) {                                         \
            float4 xv = *reinterpret_cast<const float4*>(&xs[rg * 8 + i][dq * 4]); \
            d0[i] = fmaf(xv.x, cv0.x, d0[i]);                                 \
            d0[i] = fmaf(xv.y, cv0.y, d0[i]);                                 \
            d0[i] = fmaf(xv.z, cv0.z, d0[i]);                                 \
            d0[i] = fmaf(xv.w, cv0.w, d0[i]);                                 \
            d1[i] = fmaf(xv.x, cv1.x, d1[i]);                                 \
            d1[i] = fmaf(xv.y, cv1.y, d1[i]);                                 \
            d1[i] = fmaf(xv.z, cv1.z, d1[i]);                                 \
            d1[i] = fmaf(xv.w, cv1.w, d1[i]);                                 \
        }                                                                     \
    }

__global__ __launch_bounds__(512) void rescue_kernel(
        const float* __restrict__ x, const float* __restrict__ c,
        const char* __restrict__ ws, int use_ct, int* __restrict__ out) {
    __shared__ __align__(16) float xs[16][DIM];   // 48 KB
    __shared__ float mv[16][4];
    __shared__ int   mi[16][4];
    __shared__ int   rows_s[16];
    const float* csq = (const float*)(ws + WS_CSQ);
    const int* list  = (const int*)(ws + WS_LIST);
    const float4* ct4 = (const float4*)(ws + WS_CT);
    const int n = *(const int*)ws;
    const int tid  = threadIdx.x;
    const int wv   = tid >> 6;          // wave 0..7
    const int rg   = tid >> 8;          // row group 0..1 (rows rg*8..+7)
    const int cg   = tid & 255;         // center pair id
    const int k0 = cg;                  // centers k0, k0+256 (asc for ties)
    const int k1 = cg + 256;
    const float* c0 = c + (size_t)min(k0, K_C - 1) * DIM;
    const float* c1 = c + (size_t)min(k1, K_C - 1) * DIM;
    const float cq0 = csq[k0];
    const float cq1 = csq[k1];

    for (int g = blockIdx.x; g * 16 < n; g += gridDim.x) {
        const int base = g * 16;
        const int cnt  = min(16, n - base);
        if (tid < 16) rows_s[tid] = list[base + min(tid, cnt - 1)];
        __syncthreads();
        for (int idx = tid; idx < 16 * (DIM / 4); idx += 512) {
            int r = idx / (DIM / 4), dc = idx - r * (DIM / 4);
            *reinterpret_cast<float4*>(&xs[r][dc * 4]) =
                *reinterpret_cast<const float4*>(&x[(size_t)rows_s[r] * DIM + dc * 4]);
        }
        __syncthreads();

        float d0[8], d1[8];
        #pragma unroll
        for (int i = 0; i < 8; ++i) { d0[i] = 0.f; d1[i] = 0.f; }

        if (use_ct) {
            #pragma unroll 2
            for (int dq = 0; dq < DIM / 4; ++dq) {
                float4 cv0 = ct4[(size_t)dq * 512 + cg];
                float4 cv1 = ct4[(size_t)dq * 512 + cg + 256];
                FMA_BLOCK
            }
        } else {
            #pragma unroll 2
            for (int dq = 0; dq < DIM / 4; ++dq) {
                float4 cv0 = *reinterpret_cast<const float4*>(&c0[dq * 4]);
                float4 cv1 = *reinterpret_cast<const float4*>(&c1[dq * 4]);
                FMA_BLOCK
            }
        }

        float bv[8]; int bi[8];
        #pragma unroll
        for (int i = 0; i < 8; ++i) {
            float v0 = fmaf(-2.f, d0[i], cq0);
            float v1 = fmaf(-2.f, d1[i], cq1);
            if (v1 < v0) { bv[i] = v1; bi[i] = k1; }
            else         { bv[i] = v0; bi[i] = k0; }   // k0 < k1: ties keep k0
        }
        #pragma unroll
        for (int m = 1; m < 64; m <<= 1) {
            #pragma unroll
            for (int i = 0; i < 8; ++i) {
                float ov = __shfl_xor(bv[i], m, 64);
                int   oi = __shfl_xor(bi[i], m, 64);
                if (ov < bv[i] || (ov == bv[i] && oi < bi[i])) { bv[i] = ov; bi[i] = oi; }
            }
        }
        if ((tid & 63) == 0) {
            #pragma unroll
            for (int i = 0; i < 8; ++i) { mv[rg * 8 + i][wv & 3] = bv[i]; mi[rg * 8 + i][wv & 3] = bi[i]; }
        }
        __syncthreads();
        if (tid < cnt) {
            float b = mv[tid][0]; int i = mi[tid][0];
            #pragma unroll
            for (int q = 1; q < 4; ++q) {
                if (mv[tid][q] < b || (mv[tid][q] == b && mi[tid][q] < i)) {
                    b = mv[tid][q]; i = mi[tid][q];
                }
            }
            out[rows_s[tid]] = i;
        }
        __syncthreads();
    }
}

extern "C" void kernel_launch(void* const* d_in, const int* in_sizes, int n_in,
                              void* d_out, int out_size, void* d_ws, size_t ws_size,
                              hipStream_t stream) {
    const float* x = (const float*)d_in[0];
    const float* c = (const float*)d_in[1];
    char* ws = (char*)d_ws;
    int* out = (int*)d_out;
    const int use_ct = (ws_size >= (size_t)WS_NEED) ? 1 : 0;

    convert_kernel<<<dim3(192), dim3(256), 0, stream>>>(
        c, (ushort*)(ws + WS_CHI), (float4*)(ws + WS_CT), use_ct, (int*)ws);
    csq_kernel<<<dim3(128), dim3(256), 0, stream>>>(c, (float*)(ws + WS_CSQ));
    kmeans_mfma<<<dim3(NROWS / BM), dim3(THREADS), 0, stream>>>(x, ws, out);
    rescue_kernel<<<dim3(256), dim3(512), 0, stream>>>(x, c, ws, use_ct, out);
}